// Round 5
// baseline (142.339 us; speedup 1.0000x reference)
//
#include <hip/hip_runtime.h>
#include <hip/hip_bf16.h>

#define S_LEN 4096
#define EMB   256
#define NHEAD 8
#define HDIM  32
#define WIN   64
#define BATCH 2

typedef __attribute__((ext_vector_type(8))) short short8;
typedef __attribute__((ext_vector_type(4))) float floatx4;
typedef unsigned short u16;

// ---- split-precision bf16 helpers: x = hi + lo + O(2^-18 |x|) ----
static __device__ __forceinline__ unsigned int bf16_rn(float x) {
    unsigned int u = __float_as_uint(x);
    return (u + 0x7FFFu + ((u >> 16) & 1u)) >> 16;
}
static __device__ __forceinline__ void split2(float x, unsigned int& hi, unsigned int& lo) {
    hi = bf16_rn(x);
    const float hf = __uint_as_float(hi << 16);
    lo = bf16_rn(x - hf);
}
static __device__ __forceinline__ void split_store4(u16* hp, u16* lp, float4 v) {
    unsigned int h0, l0, h1, l1, h2, l2, h3, l3;
    split2(v.x, h0, l0); split2(v.y, h1, l1);
    split2(v.z, h2, l2); split2(v.w, h3, l3);
    uint2 hv, lv;
    hv.x = h0 | (h1 << 16); hv.y = h2 | (h3 << 16);
    lv.x = l0 | (l1 << 16); lv.y = l2 | (l3 << 16);
    *(uint2*)hp = hv;
    *(uint2*)lp = lv;
}

// ============ pre-pass: fp32 -> split hi/lo bf16 for X, in_proj_w, out_w ============
#define NX4 524288   // 8192*256/4
#define NW4 49152    // 768*256/4
#define NO4 16384    // 256*256/4

__global__ __launch_bounds__(256) void convert_kernel(
    const float* __restrict__ X, const float* __restrict__ Wi, const float* __restrict__ Wo,
    u16* __restrict__ Xh, u16* __restrict__ Xl,
    u16* __restrict__ Wih, u16* __restrict__ Wil,
    u16* __restrict__ Woh, u16* __restrict__ Wol)
{
    const int i = blockIdx.x * 256 + threadIdx.x;
    const float* src; u16 *dh, *dl; int off;
    if (i < NX4)            { src = X;  dh = Xh;  dl = Xl;  off = i; }
    else if (i < NX4 + NW4) { src = Wi; dh = Wih; dl = Wil; off = i - NX4; }
    else                    { src = Wo; dh = Woh; dl = Wol; off = i - NX4 - NW4; }
    const float4 v = *(const float4*)(src + (size_t)off * 4);
    split_store4(dh + (size_t)off * 4, dl + (size_t)off * 4, v);
}

// ============ QKV GEMM (pure-bf16 staging): C[8192,768] = X * W^T ============
#define LDA 40  // u16 row stride: 80B, 16B-aligned, 2-way-free

__global__ __launch_bounds__(256) void qkv_proj_kernel(
    const u16* __restrict__ Xh, const u16* __restrict__ Xl,
    const u16* __restrict__ Wh, const u16* __restrict__ Wl,
    const float* __restrict__ bias,
    u16* __restrict__ Qh, u16* __restrict__ Ql,
    u16* __restrict__ Kh, u16* __restrict__ Kl, u16* __restrict__ Vb)
{
    __shared__ __align__(16) u16 Ah[128 * LDA], Al[128 * LDA];
    __shared__ __align__(16) u16 Bh[64 * LDA],  Bl[64 * LDA];
    const int tid = threadIdx.x;
    const int m0 = blockIdx.y * 128, n0 = blockIdx.x * 64;
    const int srow = tid >> 2, sc = tid & 3;        // staging: row, 16B-col
    const int lane = tid & 63, wv = tid >> 6;
    const int wm = (wv >> 1) * 64, wn = (wv & 1) * 32;
    const int lm = lane & 15, kq = lane >> 4;

    uint4 pah[2], pal[2], pbh, pbl;
#pragma unroll
    for (int r = 0; r < 2; ++r) {
        pah[r] = *(const uint4*)(Xh + (size_t)(m0 + srow + r * 64) * EMB + sc * 8);
        pal[r] = *(const uint4*)(Xl + (size_t)(m0 + srow + r * 64) * EMB + sc * 8);
    }
    pbh = *(const uint4*)(Wh + (size_t)(n0 + srow) * EMB + sc * 8);
    pbl = *(const uint4*)(Wl + (size_t)(n0 + srow) * EMB + sc * 8);

    floatx4 acc[4][2] = {};
    for (int t = 0; t < 8; ++t) {
        __syncthreads();
#pragma unroll
        for (int r = 0; r < 2; ++r) {
            *(uint4*)&Ah[(srow + r * 64) * LDA + sc * 8] = pah[r];
            *(uint4*)&Al[(srow + r * 64) * LDA + sc * 8] = pal[r];
        }
        *(uint4*)&Bh[srow * LDA + sc * 8] = pbh;
        *(uint4*)&Bl[srow * LDA + sc * 8] = pbl;
        __syncthreads();
        if (t < 7) {
            const int k0 = (t + 1) * 32;
#pragma unroll
            for (int r = 0; r < 2; ++r) {
                pah[r] = *(const uint4*)(Xh + (size_t)(m0 + srow + r * 64) * EMB + k0 + sc * 8);
                pal[r] = *(const uint4*)(Xl + (size_t)(m0 + srow + r * 64) * EMB + k0 + sc * 8);
            }
            pbh = *(const uint4*)(Wh + (size_t)(n0 + srow) * EMB + k0 + sc * 8);
            pbl = *(const uint4*)(Wl + (size_t)(n0 + srow) * EMB + k0 + sc * 8);
        }
        short8 a_h[4], a_l[4], b_h[2], b_l[2];
#pragma unroll
        for (int mt = 0; mt < 4; ++mt) {
            a_h[mt] = *(const short8*)&Ah[(wm + mt * 16 + lm) * LDA + kq * 8];
            a_l[mt] = *(const short8*)&Al[(wm + mt * 16 + lm) * LDA + kq * 8];
        }
#pragma unroll
        for (int nt = 0; nt < 2; ++nt) {
            b_h[nt] = *(const short8*)&Bh[(wn + nt * 16 + lm) * LDA + kq * 8];
            b_l[nt] = *(const short8*)&Bl[(wn + nt * 16 + lm) * LDA + kq * 8];
        }
#pragma unroll
        for (int mt = 0; mt < 4; ++mt)
#pragma unroll
            for (int nt = 0; nt < 2; ++nt) {
                acc[mt][nt] = __builtin_amdgcn_mfma_f32_16x16x32_bf16(a_h[mt], b_h[nt], acc[mt][nt], 0, 0, 0);
                acc[mt][nt] = __builtin_amdgcn_mfma_f32_16x16x32_bf16(a_h[mt], b_l[nt], acc[mt][nt], 0, 0, 0);
                acc[mt][nt] = __builtin_amdgcn_mfma_f32_16x16x32_bf16(a_l[mt], b_h[nt], acc[mt][nt], 0, 0, 0);
            }
    }
    // epilogue: write Q,K split-bf16 (Q pre-scaled), V plain bf16, [B,H,S,D]
#pragma unroll
    for (int nt = 0; nt < 2; ++nt) {
        const int f = n0 + wn + nt * 16 + lm;
        const int which = f >> 8;
        const int h = (f & 255) >> 5, d = f & 31;
        const float sc2 = (which == 0) ? 0.17677669529663687f : 1.0f;
        const float bf = bias[f];
#pragma unroll
        for (int mt = 0; mt < 4; ++mt)
#pragma unroll
            for (int r = 0; r < 4; ++r) {
                const int m = m0 + wm + mt * 16 + kq * 4 + r;
                const int b = m >> 12, s = m & (S_LEN - 1);
                const float v = (acc[mt][nt][r] + bf) * sc2;
                const size_t off = (((size_t)b * NHEAD + h) * S_LEN + s) * HDIM + d;
                if (which == 2) {
                    Vb[off] = (u16)bf16_rn(v);
                } else {
                    unsigned int hi, lo;
                    split2(v, hi, lo);
                    if (which == 0) { Qh[off] = (u16)hi; Ql[off] = (u16)lo; }
                    else            { Kh[off] = (u16)hi; Kl[off] = (u16)lo; }
                }
            }
    }
}

// ============ OUT GEMM (pure-bf16 staging): out[8192,256] = Ab * Wo^T + b ============
__global__ __launch_bounds__(256) void out_proj_kernel(
    const u16* __restrict__ Abh, const u16* __restrict__ Abl,
    const u16* __restrict__ Wh, const u16* __restrict__ Wl,
    const float* __restrict__ bias, float* __restrict__ C)
{
    __shared__ __align__(16) u16 Ah[128 * LDA], Al[128 * LDA];
    __shared__ __align__(16) u16 Bh[64 * LDA],  Bl[64 * LDA];
    const int tid = threadIdx.x;
    const int m0 = blockIdx.y * 128, n0 = blockIdx.x * 64;
    const int srow = tid >> 2, sc = tid & 3;
    const int lane = tid & 63, wv = tid >> 6;
    const int wm = (wv >> 1) * 64, wn = (wv & 1) * 32;
    const int lm = lane & 15, kq = lane >> 4;

    uint4 pah[2], pal[2], pbh, pbl;
#pragma unroll
    for (int r = 0; r < 2; ++r) {
        pah[r] = *(const uint4*)(Abh + (size_t)(m0 + srow + r * 64) * EMB + sc * 8);
        pal[r] = *(const uint4*)(Abl + (size_t)(m0 + srow + r * 64) * EMB + sc * 8);
    }
    pbh = *(const uint4*)(Wh + (size_t)(n0 + srow) * EMB + sc * 8);
    pbl = *(const uint4*)(Wl + (size_t)(n0 + srow) * EMB + sc * 8);

    floatx4 acc[4][2] = {};
    for (int t = 0; t < 8; ++t) {
        __syncthreads();
#pragma unroll
        for (int r = 0; r < 2; ++r) {
            *(uint4*)&Ah[(srow + r * 64) * LDA + sc * 8] = pah[r];
            *(uint4*)&Al[(srow + r * 64) * LDA + sc * 8] = pal[r];
        }
        *(uint4*)&Bh[srow * LDA + sc * 8] = pbh;
        *(uint4*)&Bl[srow * LDA + sc * 8] = pbl;
        __syncthreads();
        if (t < 7) {
            const int k0 = (t + 1) * 32;
#pragma unroll
            for (int r = 0; r < 2; ++r) {
                pah[r] = *(const uint4*)(Abh + (size_t)(m0 + srow + r * 64) * EMB + k0 + sc * 8);
                pal[r] = *(const uint4*)(Abl + (size_t)(m0 + srow + r * 64) * EMB + k0 + sc * 8);
            }
            pbh = *(const uint4*)(Wh + (size_t)(n0 + srow) * EMB + k0 + sc * 8);
            pbl = *(const uint4*)(Wl + (size_t)(n0 + srow) * EMB + k0 + sc * 8);
        }
        short8 a_h[4], a_l[4], b_h[2], b_l[2];
#pragma unroll
        for (int mt = 0; mt < 4; ++mt) {
            a_h[mt] = *(const short8*)&Ah[(wm + mt * 16 + lm) * LDA + kq * 8];
            a_l[mt] = *(const short8*)&Al[(wm + mt * 16 + lm) * LDA + kq * 8];
        }
#pragma unroll
        for (int nt = 0; nt < 2; ++nt) {
            b_h[nt] = *(const short8*)&Bh[(wn + nt * 16 + lm) * LDA + kq * 8];
            b_l[nt] = *(const short8*)&Bl[(wn + nt * 16 + lm) * LDA + kq * 8];
        }
#pragma unroll
        for (int mt = 0; mt < 4; ++mt)
#pragma unroll
            for (int nt = 0; nt < 2; ++nt) {
                acc[mt][nt] = __builtin_amdgcn_mfma_f32_16x16x32_bf16(a_h[mt], b_h[nt], acc[mt][nt], 0, 0, 0);
                acc[mt][nt] = __builtin_amdgcn_mfma_f32_16x16x32_bf16(a_h[mt], b_l[nt], acc[mt][nt], 0, 0, 0);
                acc[mt][nt] = __builtin_amdgcn_mfma_f32_16x16x32_bf16(a_l[mt], b_h[nt], acc[mt][nt], 0, 0, 0);
            }
    }
#pragma unroll
    for (int nt = 0; nt < 2; ++nt) {
        const int f = n0 + wn + nt * 16 + lm;
        const float bf = bias[f];
#pragma unroll
        for (int mt = 0; mt < 4; ++mt)
#pragma unroll
            for (int r = 0; r < 4; ++r) {
                const int m = m0 + wm + mt * 16 + kq * 4 + r;
                C[(size_t)m * EMB + f] = acc[mt][nt][r] + bf;
            }
    }
}

// ================= Banded attention (MFMA, bf16-staged) =================
#define AKS 40   // Q/K row stride (u16)
#define AVS 200  // Vt row stride (u16)
#define APS 200  // P row stride (u16)

__global__ __launch_bounds__(256) void local_attn_kernel(
    const u16* __restrict__ Qhg, const u16* __restrict__ Qlg,
    const u16* __restrict__ Khg, const u16* __restrict__ Klg,
    const u16* __restrict__ Vbg,
    u16* __restrict__ Abh, u16* __restrict__ Abl)
{
    __shared__ __align__(16) u16 Qh[64 * AKS], Ql[64 * AKS];
    __shared__ __align__(16) u16 Kh[192 * AKS], Kl[192 * AKS];
    __shared__ __align__(16) u16 Vt[32 * AVS];
    __shared__ __align__(16) u16 Pw[4 * 16 * APS];

    const int tid = threadIdx.x;
    const int q0 = blockIdx.x * 64;
    const int h = blockIdx.y, b = blockIdx.z;
    const int jmin = max(0, q0 - WIN);
    const int jmax = min(S_LEN - 1, q0 + 63 + WIN);
    const int nk = jmax - jmin + 1;                  // <= 192
    const size_t bhS = ((size_t)b * NHEAD + h) * S_LEN;
    const size_t qoff = (bhS + q0) * HDIM;
    const size_t koff = (bhS + jmin) * HDIM;

    const int srow = tid >> 2, sc = tid & 3;         // row, 16B-col (8 u16)
    // stage Q (64x32, hi+lo): 1 pass each
    {
        const uint4 vh = *(const uint4*)(Qhg + qoff + (size_t)srow * HDIM + sc * 8);
        const uint4 vl = *(const uint4*)(Qlg + qoff + (size_t)srow * HDIM + sc * 8);
        *(uint4*)&Qh[srow * AKS + sc * 8] = vh;
        *(uint4*)&Ql[srow * AKS + sc * 8] = vl;
    }
    // stage K (192 slots, hi+lo): 3 passes, tail clamped (masked later)
#pragma unroll
    for (int r = 0; r < 3; ++r) {
        const int t = srow + r * 64;
        const int tc = min(t, nk - 1);
        const uint4 vh = *(const uint4*)(Khg + koff + (size_t)tc * HDIM + sc * 8);
        const uint4 vl = *(const uint4*)(Klg + koff + (size_t)tc * HDIM + sc * 8);
        *(uint4*)&Kh[t * AKS + sc * 8] = vh;
        *(uint4*)&Kl[t * AKS + sc * 8] = vl;
    }
    // stage V transposed: Vt[dim][slot]
#pragma unroll
    for (int r = 0; r < 3; ++r) {
        const int t = srow + r * 64;
        const int tc = min(t, nk - 1);
        const uint4 v = *(const uint4*)(Vbg + koff + (size_t)tc * HDIM + sc * 8);
        const int d0 = sc * 8;
        Vt[(d0 + 0) * AVS + t] = (u16)(v.x & 0xFFFF);
        Vt[(d0 + 1) * AVS + t] = (u16)(v.x >> 16);
        Vt[(d0 + 2) * AVS + t] = (u16)(v.y & 0xFFFF);
        Vt[(d0 + 3) * AVS + t] = (u16)(v.y >> 16);
        Vt[(d0 + 4) * AVS + t] = (u16)(v.z & 0xFFFF);
        Vt[(d0 + 5) * AVS + t] = (u16)(v.z >> 16);
        Vt[(d0 + 6) * AVS + t] = (u16)(v.w & 0xFFFF);
        Vt[(d0 + 7) * AVS + t] = (u16)(v.w >> 16);
    }
    __syncthreads();

    const int lane = tid & 63, wv = tid >> 6;
    const int lm = lane & 15, quad = lane >> 4;
    const int qbase = wv * 16;

    const short8 qh = *(const short8*)&Qh[(qbase + lm) * AKS + quad * 8];
    const short8 ql = *(const short8*)&Ql[(qbase + lm) * AKS + quad * 8];

    floatx4 sacc[12];
#pragma unroll
    for (int nt = 0; nt < 12; ++nt) {
        const short8 bh = *(const short8*)&Kh[(nt * 16 + lm) * AKS + quad * 8];
        const short8 bl = *(const short8*)&Kl[(nt * 16 + lm) * AKS + quad * 8];
        floatx4 a = {};
        a = __builtin_amdgcn_mfma_f32_16x16x32_bf16(qh, bh, a, 0, 0, 0);
        a = __builtin_amdgcn_mfma_f32_16x16x32_bf16(qh, bl, a, 0, 0, 0);
        a = __builtin_amdgcn_mfma_f32_16x16x32_bf16(ql, bh, a, 0, 0, 0);
        sacc[nt] = a;
    }

    const int qg = q0 + qbase + quad * 4;
    float mx[4] = {-1e30f, -1e30f, -1e30f, -1e30f};
#pragma unroll
    for (int nt = 0; nt < 12; ++nt) {
        const int slot = nt * 16 + lm;
        const int keyg = jmin + slot;
#pragma unroll
        for (int r = 0; r < 4; ++r) {
            const int qr = qg + r;
            const bool valid = (slot < nk) && (keyg >= qr - WIN) && (keyg <= qr + WIN);
            const float sv = valid ? sacc[nt][r] : -1e30f;
            sacc[nt][r] = sv;
            mx[r] = fmaxf(mx[r], sv);
        }
    }
#pragma unroll
    for (int r = 0; r < 4; ++r) {
        mx[r] = fmaxf(mx[r], __shfl_xor(mx[r], 1));
        mx[r] = fmaxf(mx[r], __shfl_xor(mx[r], 2));
        mx[r] = fmaxf(mx[r], __shfl_xor(mx[r], 4));
        mx[r] = fmaxf(mx[r], __shfl_xor(mx[r], 8));
    }
    float l[4] = {0.f, 0.f, 0.f, 0.f};
    u16* Pme = &Pw[wv * 16 * APS];
#pragma unroll
    for (int nt = 0; nt < 12; ++nt)
#pragma unroll
        for (int r = 0; r < 4; ++r) {
            const float p = __expf(sacc[nt][r] - mx[r]);
            l[r] += p;
            Pme[(quad * 4 + r) * APS + nt * 16 + lm] = (u16)bf16_rn(p);
        }
#pragma unroll
    for (int r = 0; r < 4; ++r) {
        l[r] += __shfl_xor(l[r], 1);
        l[r] += __shfl_xor(l[r], 2);
        l[r] += __shfl_xor(l[r], 4);
        l[r] += __shfl_xor(l[r], 8);
    }
    const float rl[4] = {1.f / l[0], 1.f / l[1], 1.f / l[2], 1.f / l[3]};

    floatx4 oacc[2] = {};
#pragma unroll
    for (int ks = 0; ks < 6; ++ks) {
        const short8 ap  = *(const short8*)&Pme[lm * APS + ks * 32 + quad * 8];
        const short8 bv0 = *(const short8*)&Vt[lm * AVS + ks * 32 + quad * 8];
        const short8 bv1 = *(const short8*)&Vt[(16 + lm) * AVS + ks * 32 + quad * 8];
        oacc[0] = __builtin_amdgcn_mfma_f32_16x16x32_bf16(ap, bv0, oacc[0], 0, 0, 0);
        oacc[1] = __builtin_amdgcn_mfma_f32_16x16x32_bf16(ap, bv1, oacc[1], 0, 0, 0);
    }
    // epilogue: Ab as split-bf16, [B,S,E]
#pragma unroll
    for (int nt = 0; nt < 2; ++nt)
#pragma unroll
        for (int r = 0; r < 4; ++r) {
            const int qrow = qbase + quad * 4 + r;
            const float v = oacc[nt][r] * rl[r];
            unsigned int hi, lo;
            split2(v, hi, lo);
            const size_t off = ((size_t)b * S_LEN + q0 + qrow) * EMB + h * HDIM + nt * 16 + lm;
            Abh[off] = (u16)hi;
            Abl[off] = (u16)lo;
        }
}

extern "C" void kernel_launch(void* const* d_in, const int* in_sizes, int n_in,
                              void* d_out, int out_size, void* d_ws, size_t ws_size,
                              hipStream_t stream) {
    const float* x  = (const float*)d_in[0];
    const float* wi = (const float*)d_in[1];
    const float* bi = (const float*)d_in[2];
    const float* wo = (const float*)d_in[3];
    const float* bo = (const float*)d_in[4];
    float* out = (float*)d_out;

    const size_t per = (size_t)BATCH * NHEAD * S_LEN * HDIM; // 2,097,152
    u16* p = (u16*)d_ws;
    u16* Xh  = p; p += per;
    u16* Xl  = p; p += per;
    u16* Wih = p; p += 768 * EMB;
    u16* Wil = p; p += 768 * EMB;
    u16* Woh = p; p += EMB * EMB;
    u16* Wol = p; p += EMB * EMB;
    u16* Qh  = p; p += per;
    u16* Ql  = p; p += per;
    u16* Kh  = p; p += per;
    u16* Kl  = p; p += per;
    u16* Vb  = p; p += per;
    u16* Abh = p; p += per;
    u16* Abl = p; p += per;

    convert_kernel<<<dim3((NX4 + NW4 + NO4) / 256), 256, 0, stream>>>(
        x, wi, wo, Xh, Xl, Wih, Wil, Woh, Wol);
    qkv_proj_kernel<<<dim3(768 / 64, 8192 / 128), 256, 0, stream>>>(
        Xh, Xl, Wih, Wil, bi, Qh, Ql, Kh, Kl, Vb);
    local_attn_kernel<<<dim3(S_LEN / 64, NHEAD, BATCH), 256, 0, stream>>>(
        Qh, Ql, Kh, Kl, Vb, Abh, Abl);
    out_proj_kernel<<<dim3(256 / 64, 8192 / 128), 256, 0, stream>>>(
        Abh, Abl, Woh, Wol, bo, out);
}

// Round 6
// 112.261 us; speedup vs baseline: 1.2679x; 1.2679x over previous
//
#include <hip/hip_runtime.h>
#include <hip/hip_bf16.h>

#define S_LEN 4096
#define EMB   256
#define NHEAD 8
#define HDIM  32
#define WIN   64
#define BATCH 2

typedef __attribute__((ext_vector_type(8))) short short8;
typedef __attribute__((ext_vector_type(4))) float floatx4;
typedef unsigned short u16;
typedef unsigned int   u32;

// ---- split-precision bf16, packed as u32 = (hi<<16)|lo; x = hi + lo + O(2^-18 |x|) ----
static __device__ __forceinline__ u32 bf16_rn(float x) {
    u32 u = __float_as_uint(x);
    return (u + 0x7FFFu + ((u >> 16) & 1u)) >> 16;
}
static __device__ __forceinline__ u32 packsplit(float x) {
    const u32 hi = bf16_rn(x);
    const float hf = __uint_as_float(hi << 16);
    const u32 lo = bf16_rn(x - hf);
    return (hi << 16) | lo;
}
// two packed elems -> (hi0,hi1) u32 and (lo0,lo1) u32 (little-endian u16 order)
static __device__ __forceinline__ void unpack_pair(u32 p0, u32 p1, u32& h, u32& l) {
    h = (p0 >> 16) | (p1 & 0xFFFF0000u);
    l = (p0 & 0xFFFFu) | (p1 << 16);
}
static __device__ __forceinline__ void unpack8(uint4 a, uint4 b, uint4& h, uint4& l) {
    unpack_pair(a.x, a.y, h.x, l.x);
    unpack_pair(a.z, a.w, h.y, l.y);
    unpack_pair(b.x, b.y, h.z, l.z);
    unpack_pair(b.z, b.w, h.w, l.w);
}

// ============ pre-pass: fp32 -> packed split-bf16 for X, in_proj_w, out_w ============
#define NX4 524288   // 8192*256/4
#define NW4 49152    // 768*256/4
#define NO4 16384    // 256*256/4

__global__ __launch_bounds__(256) void convert_kernel(
    const float* __restrict__ X, const float* __restrict__ Wi, const float* __restrict__ Wo,
    u32* __restrict__ Xp, u32* __restrict__ Wip, u32* __restrict__ Wop)
{
    const int i = blockIdx.x * 256 + threadIdx.x;
    const float* src; u32* dst; int off;
    if (i < NX4)            { src = X;  dst = Xp;  off = i; }
    else if (i < NX4 + NW4) { src = Wi; dst = Wip; off = i - NX4; }
    else                    { src = Wo; dst = Wop; off = i - NX4 - NW4; }
    const float4 v = *(const float4*)(src + (size_t)off * 4);
    uint4 o;
    o.x = packsplit(v.x); o.y = packsplit(v.y);
    o.z = packsplit(v.z); o.w = packsplit(v.w);
    *(uint4*)(dst + (size_t)off * 4) = o;
}

// ============ QKV GEMM: C[8192,768] = X * W^T, packed-u32 in/out ============
#define LDA 40  // u16 row stride: 80B, 16B-aligned, 2-way-free

__global__ __launch_bounds__(256) void qkv_proj_kernel(
    const u32* __restrict__ Xp, const u32* __restrict__ Wp,
    const float* __restrict__ bias,
    u32* __restrict__ Qp, u32* __restrict__ Kp, u32* __restrict__ Vp)
{
    __shared__ __align__(16) u16 Ah[128 * LDA], Al[128 * LDA];
    __shared__ __align__(16) u16 Bh[64 * LDA],  Bl[64 * LDA];
    const int tid = threadIdx.x;
    const int m0 = blockIdx.y * 128, n0 = blockIdx.x * 64;
    const int srow = tid >> 2, sc = tid & 3;        // staging: row, 8-elem col
    const int lane = tid & 63, wv = tid >> 6;
    const int wm = (wv >> 1) * 64, wn = (wv & 1) * 32;
    const int lm = lane & 15, kq = lane >> 4;

    uint4 pA[2][2], pB[2];
#pragma unroll
    for (int r = 0; r < 2; ++r) {
        const u32* base = Xp + (size_t)(m0 + srow + r * 64) * EMB + sc * 8;
        pA[r][0] = *(const uint4*)base;
        pA[r][1] = *(const uint4*)(base + 4);
    }
    {
        const u32* base = Wp + (size_t)(n0 + srow) * EMB + sc * 8;
        pB[0] = *(const uint4*)base;
        pB[1] = *(const uint4*)(base + 4);
    }

    floatx4 acc[4][2] = {};
    for (int t = 0; t < 8; ++t) {
        __syncthreads();
#pragma unroll
        for (int r = 0; r < 2; ++r) {
            uint4 h, l;
            unpack8(pA[r][0], pA[r][1], h, l);
            *(uint4*)&Ah[(srow + r * 64) * LDA + sc * 8] = h;
            *(uint4*)&Al[(srow + r * 64) * LDA + sc * 8] = l;
        }
        {
            uint4 h, l;
            unpack8(pB[0], pB[1], h, l);
            *(uint4*)&Bh[srow * LDA + sc * 8] = h;
            *(uint4*)&Bl[srow * LDA + sc * 8] = l;
        }
        __syncthreads();
        if (t < 7) {
            const int k0 = (t + 1) * 32;
#pragma unroll
            for (int r = 0; r < 2; ++r) {
                const u32* base = Xp + (size_t)(m0 + srow + r * 64) * EMB + k0 + sc * 8;
                pA[r][0] = *(const uint4*)base;
                pA[r][1] = *(const uint4*)(base + 4);
            }
            const u32* base = Wp + (size_t)(n0 + srow) * EMB + k0 + sc * 8;
            pB[0] = *(const uint4*)base;
            pB[1] = *(const uint4*)(base + 4);
        }
        short8 a_h[4], a_l[4], b_h[2], b_l[2];
#pragma unroll
        for (int mt = 0; mt < 4; ++mt) {
            a_h[mt] = *(const short8*)&Ah[(wm + mt * 16 + lm) * LDA + kq * 8];
            a_l[mt] = *(const short8*)&Al[(wm + mt * 16 + lm) * LDA + kq * 8];
        }
#pragma unroll
        for (int nt = 0; nt < 2; ++nt) {
            b_h[nt] = *(const short8*)&Bh[(wn + nt * 16 + lm) * LDA + kq * 8];
            b_l[nt] = *(const short8*)&Bl[(wn + nt * 16 + lm) * LDA + kq * 8];
        }
#pragma unroll
        for (int mt = 0; mt < 4; ++mt)
#pragma unroll
            for (int nt = 0; nt < 2; ++nt) {
                acc[mt][nt] = __builtin_amdgcn_mfma_f32_16x16x32_bf16(a_h[mt], b_h[nt], acc[mt][nt], 0, 0, 0);
                acc[mt][nt] = __builtin_amdgcn_mfma_f32_16x16x32_bf16(a_h[mt], b_l[nt], acc[mt][nt], 0, 0, 0);
                acc[mt][nt] = __builtin_amdgcn_mfma_f32_16x16x32_bf16(a_l[mt], b_h[nt], acc[mt][nt], 0, 0, 0);
            }
    }
    // epilogue: packed u32 stores, 4B/lane x 16 consecutive d -> full 64B lines
#pragma unroll
    for (int nt = 0; nt < 2; ++nt) {
        const int f = n0 + wn + nt * 16 + lm;
        const int which = f >> 8;
        const int h = (f & 255) >> 5, d = f & 31;
        u32* dst = (which == 0) ? Qp : ((which == 1) ? Kp : Vp);
        const float sc2 = (which == 0) ? 0.17677669529663687f : 1.0f;
        const float bf = bias[f];
#pragma unroll
        for (int mt = 0; mt < 4; ++mt)
#pragma unroll
            for (int r = 0; r < 4; ++r) {
                const int m = m0 + wm + mt * 16 + kq * 4 + r;
                const int b = m >> 12, s = m & (S_LEN - 1);
                dst[(((size_t)b * NHEAD + h) * S_LEN + s) * HDIM + d]
                    = packsplit((acc[mt][nt][r] + bf) * sc2);
            }
    }
}

// ============ OUT GEMM: out[8192,256] = Ab * Wo^T + b, packed-u32 inputs, fp32 out ============
__global__ __launch_bounds__(256) void out_proj_kernel(
    const u32* __restrict__ Abp, const u32* __restrict__ Wp,
    const float* __restrict__ bias, float* __restrict__ C)
{
    __shared__ __align__(16) u16 Ah[128 * LDA], Al[128 * LDA];
    __shared__ __align__(16) u16 Bh[64 * LDA],  Bl[64 * LDA];
    const int tid = threadIdx.x;
    const int m0 = blockIdx.y * 128, n0 = blockIdx.x * 64;
    const int srow = tid >> 2, sc = tid & 3;
    const int lane = tid & 63, wv = tid >> 6;
    const int wm = (wv >> 1) * 64, wn = (wv & 1) * 32;
    const int lm = lane & 15, kq = lane >> 4;

    uint4 pA[2][2], pB[2];
#pragma unroll
    for (int r = 0; r < 2; ++r) {
        const u32* base = Abp + (size_t)(m0 + srow + r * 64) * EMB + sc * 8;
        pA[r][0] = *(const uint4*)base;
        pA[r][1] = *(const uint4*)(base + 4);
    }
    {
        const u32* base = Wp + (size_t)(n0 + srow) * EMB + sc * 8;
        pB[0] = *(const uint4*)base;
        pB[1] = *(const uint4*)(base + 4);
    }

    floatx4 acc[4][2] = {};
    for (int t = 0; t < 8; ++t) {
        __syncthreads();
#pragma unroll
        for (int r = 0; r < 2; ++r) {
            uint4 h, l;
            unpack8(pA[r][0], pA[r][1], h, l);
            *(uint4*)&Ah[(srow + r * 64) * LDA + sc * 8] = h;
            *(uint4*)&Al[(srow + r * 64) * LDA + sc * 8] = l;
        }
        {
            uint4 h, l;
            unpack8(pB[0], pB[1], h, l);
            *(uint4*)&Bh[srow * LDA + sc * 8] = h;
            *(uint4*)&Bl[srow * LDA + sc * 8] = l;
        }
        __syncthreads();
        if (t < 7) {
            const int k0 = (t + 1) * 32;
#pragma unroll
            for (int r = 0; r < 2; ++r) {
                const u32* base = Abp + (size_t)(m0 + srow + r * 64) * EMB + k0 + sc * 8;
                pA[r][0] = *(const uint4*)base;
                pA[r][1] = *(const uint4*)(base + 4);
            }
            const u32* base = Wp + (size_t)(n0 + srow) * EMB + k0 + sc * 8;
            pB[0] = *(const uint4*)base;
            pB[1] = *(const uint4*)(base + 4);
        }
        short8 a_h[4], a_l[4], b_h[2], b_l[2];
#pragma unroll
        for (int mt = 0; mt < 4; ++mt) {
            a_h[mt] = *(const short8*)&Ah[(wm + mt * 16 + lm) * LDA + kq * 8];
            a_l[mt] = *(const short8*)&Al[(wm + mt * 16 + lm) * LDA + kq * 8];
        }
#pragma unroll
        for (int nt = 0; nt < 2; ++nt) {
            b_h[nt] = *(const short8*)&Bh[(wn + nt * 16 + lm) * LDA + kq * 8];
            b_l[nt] = *(const short8*)&Bl[(wn + nt * 16 + lm) * LDA + kq * 8];
        }
#pragma unroll
        for (int mt = 0; mt < 4; ++mt)
#pragma unroll
            for (int nt = 0; nt < 2; ++nt) {
                acc[mt][nt] = __builtin_amdgcn_mfma_f32_16x16x32_bf16(a_h[mt], b_h[nt], acc[mt][nt], 0, 0, 0);
                acc[mt][nt] = __builtin_amdgcn_mfma_f32_16x16x32_bf16(a_h[mt], b_l[nt], acc[mt][nt], 0, 0, 0);
                acc[mt][nt] = __builtin_amdgcn_mfma_f32_16x16x32_bf16(a_l[mt], b_h[nt], acc[mt][nt], 0, 0, 0);
            }
    }
#pragma unroll
    for (int nt = 0; nt < 2; ++nt) {
        const int f = n0 + wn + nt * 16 + lm;
        const float bf = bias[f];
#pragma unroll
        for (int mt = 0; mt < 4; ++mt)
#pragma unroll
            for (int r = 0; r < 4; ++r) {
                const int m = m0 + wm + mt * 16 + kq * 4 + r;
                C[(size_t)m * EMB + f] = acc[mt][nt][r] + bf;
            }
    }
}

// ================= Banded attention (MFMA, packed-u32 I/O) =================
#define AKS 40   // Q/K row stride (u16)
#define AVS 200  // Vt row stride (u16)
#define APS 200  // P row stride (u16)

__global__ __launch_bounds__(256) void local_attn_kernel(
    const u32* __restrict__ Qp, const u32* __restrict__ Kp,
    const u32* __restrict__ Vp, u32* __restrict__ Abp)
{
    __shared__ __align__(16) u16 Qh[64 * AKS], Ql[64 * AKS];
    __shared__ __align__(16) u16 Kh[192 * AKS], Kl[192 * AKS];
    __shared__ __align__(16) u16 Vt[32 * AVS];
    __shared__ __align__(16) u16 Pw[4 * 16 * APS];

    const int tid = threadIdx.x;
    const int q0 = blockIdx.x * 64;
    const int h = blockIdx.y, b = blockIdx.z;
    const int jmin = max(0, q0 - WIN);
    const int jmax = min(S_LEN - 1, q0 + 63 + WIN);
    const int nk = jmax - jmin + 1;                  // <= 192
    const size_t bhS = ((size_t)b * NHEAD + h) * S_LEN;
    const size_t qoff = (bhS + q0) * HDIM;
    const size_t koff = (bhS + jmin) * HDIM;

    const int srow = tid >> 2, sc = tid & 3;
    // stage Q (64x32): unpack packed -> hi/lo LDS
    {
        const u32* base = Qp + qoff + (size_t)srow * HDIM + sc * 8;
        uint4 h4, l4;
        unpack8(*(const uint4*)base, *(const uint4*)(base + 4), h4, l4);
        *(uint4*)&Qh[srow * AKS + sc * 8] = h4;
        *(uint4*)&Ql[srow * AKS + sc * 8] = l4;
    }
    // stage K (192 slots): 3 passes, tail clamped (masked later)
#pragma unroll
    for (int r = 0; r < 3; ++r) {
        const int t = srow + r * 64;
        const int tc = min(t, nk - 1);
        const u32* base = Kp + koff + (size_t)tc * HDIM + sc * 8;
        uint4 h4, l4;
        unpack8(*(const uint4*)base, *(const uint4*)(base + 4), h4, l4);
        *(uint4*)&Kh[t * AKS + sc * 8] = h4;
        *(uint4*)&Kl[t * AKS + sc * 8] = l4;
    }
    // stage V transposed (hi halves only): Vt[dim][slot]
#pragma unroll
    for (int r = 0; r < 3; ++r) {
        const int t = srow + r * 64;
        const int tc = min(t, nk - 1);
        const u32* base = Vp + koff + (size_t)tc * HDIM + sc * 8;
        const uint4 v0 = *(const uint4*)base;
        const uint4 v1 = *(const uint4*)(base + 4);
        const int d0 = sc * 8;
        Vt[(d0 + 0) * AVS + t] = (u16)(v0.x >> 16);
        Vt[(d0 + 1) * AVS + t] = (u16)(v0.y >> 16);
        Vt[(d0 + 2) * AVS + t] = (u16)(v0.z >> 16);
        Vt[(d0 + 3) * AVS + t] = (u16)(v0.w >> 16);
        Vt[(d0 + 4) * AVS + t] = (u16)(v1.x >> 16);
        Vt[(d0 + 5) * AVS + t] = (u16)(v1.y >> 16);
        Vt[(d0 + 6) * AVS + t] = (u16)(v1.z >> 16);
        Vt[(d0 + 7) * AVS + t] = (u16)(v1.w >> 16);
    }
    __syncthreads();

    const int lane = tid & 63, wv = tid >> 6;
    const int lm = lane & 15, quad = lane >> 4;
    const int qbase = wv * 16;

    const short8 qh = *(const short8*)&Qh[(qbase + lm) * AKS + quad * 8];
    const short8 ql = *(const short8*)&Ql[(qbase + lm) * AKS + quad * 8];

    floatx4 sacc[12];
#pragma unroll
    for (int nt = 0; nt < 12; ++nt) {
        const short8 bh = *(const short8*)&Kh[(nt * 16 + lm) * AKS + quad * 8];
        const short8 bl = *(const short8*)&Kl[(nt * 16 + lm) * AKS + quad * 8];
        floatx4 a = {};
        a = __builtin_amdgcn_mfma_f32_16x16x32_bf16(qh, bh, a, 0, 0, 0);
        a = __builtin_amdgcn_mfma_f32_16x16x32_bf16(qh, bl, a, 0, 0, 0);
        a = __builtin_amdgcn_mfma_f32_16x16x32_bf16(ql, bh, a, 0, 0, 0);
        sacc[nt] = a;
    }

    const int qg = q0 + qbase + quad * 4;
    float mx[4] = {-1e30f, -1e30f, -1e30f, -1e30f};
#pragma unroll
    for (int nt = 0; nt < 12; ++nt) {
        const int slot = nt * 16 + lm;
        const int keyg = jmin + slot;
#pragma unroll
        for (int r = 0; r < 4; ++r) {
            const int qr = qg + r;
            const bool valid = (slot < nk) && (keyg >= qr - WIN) && (keyg <= qr + WIN);
            const float sv = valid ? sacc[nt][r] : -1e30f;
            sacc[nt][r] = sv;
            mx[r] = fmaxf(mx[r], sv);
        }
    }
#pragma unroll
    for (int r = 0; r < 4; ++r) {
        mx[r] = fmaxf(mx[r], __shfl_xor(mx[r], 1));
        mx[r] = fmaxf(mx[r], __shfl_xor(mx[r], 2));
        mx[r] = fmaxf(mx[r], __shfl_xor(mx[r], 4));
        mx[r] = fmaxf(mx[r], __shfl_xor(mx[r], 8));
    }
    float l[4] = {0.f, 0.f, 0.f, 0.f};
    u16* Pme = &Pw[wv * 16 * APS];
#pragma unroll
    for (int nt = 0; nt < 12; ++nt)
#pragma unroll
        for (int r = 0; r < 4; ++r) {
            const float p = __expf(sacc[nt][r] - mx[r]);
            l[r] += p;
            Pme[(quad * 4 + r) * APS + nt * 16 + lm] = (u16)bf16_rn(p);
        }
#pragma unroll
    for (int r = 0; r < 4; ++r) {
        l[r] += __shfl_xor(l[r], 1);
        l[r] += __shfl_xor(l[r], 2);
        l[r] += __shfl_xor(l[r], 4);
        l[r] += __shfl_xor(l[r], 8);
    }
    const float rl[4] = {1.f / l[0], 1.f / l[1], 1.f / l[2], 1.f / l[3]};

    floatx4 oacc[2] = {};
#pragma unroll
    for (int ks = 0; ks < 6; ++ks) {
        const short8 ap  = *(const short8*)&Pme[lm * APS + ks * 32 + quad * 8];
        const short8 bv0 = *(const short8*)&Vt[lm * AVS + ks * 32 + quad * 8];
        const short8 bv1 = *(const short8*)&Vt[(16 + lm) * AVS + ks * 32 + quad * 8];
        oacc[0] = __builtin_amdgcn_mfma_f32_16x16x32_bf16(ap, bv0, oacc[0], 0, 0, 0);
        oacc[1] = __builtin_amdgcn_mfma_f32_16x16x32_bf16(ap, bv1, oacc[1], 0, 0, 0);
    }
    // epilogue: Ab packed u32, 4B/lane x 16 consecutive -> full lines
#pragma unroll
    for (int nt = 0; nt < 2; ++nt)
#pragma unroll
        for (int r = 0; r < 4; ++r) {
            const int qrow = qbase + quad * 4 + r;
            Abp[((size_t)b * S_LEN + q0 + qrow) * EMB + h * HDIM + nt * 16 + lm]
                = packsplit(oacc[nt][r] * rl[r]);
        }
}

extern "C" void kernel_launch(void* const* d_in, const int* in_sizes, int n_in,
                              void* d_out, int out_size, void* d_ws, size_t ws_size,
                              hipStream_t stream) {
    const float* x  = (const float*)d_in[0];
    const float* wi = (const float*)d_in[1];
    const float* bi = (const float*)d_in[2];
    const float* wo = (const float*)d_in[3];
    const float* bo = (const float*)d_in[4];
    float* out = (float*)d_out;

    const size_t per = (size_t)BATCH * NHEAD * S_LEN * HDIM; // 2,097,152
    u32* p = (u32*)d_ws;
    u32* Xp  = p; p += per;
    u32* Wip = p; p += 768 * EMB;
    u32* Wop = p; p += EMB * EMB;
    u32* Qp  = p; p += per;
    u32* Kp  = p; p += per;
    u32* Vp  = p; p += per;
    u32* Abp = p; p += per;

    convert_kernel<<<dim3((NX4 + NW4 + NO4) / 256), 256, 0, stream>>>(
        x, wi, wo, Xp, Wip, Wop);
    qkv_proj_kernel<<<dim3(768 / 64, 8192 / 128), 256, 0, stream>>>(
        Xp, Wip, bi, Qp, Kp, Vp);
    local_attn_kernel<<<dim3(S_LEN / 64, NHEAD, BATCH), 256, 0, stream>>>(
        Qp, Kp, Vp, Abp);
    out_proj_kernel<<<dim3(256 / 64, 8192 / 128), 256, 0, stream>>>(
        Abp, Wop, bo, out);
}